// Round 16
// baseline (138.074 us; speedup 1.0000x reference)
//
#include <hip/hip_runtime.h>

#define DIM 1024
#define NHEADS 16
#define HDIM 64
#define BATCH 2
#define SEQ 2048
#define MTOT (BATCH*SEQ)
// 1/sqrt(64) * log2(e), folded into Q so softmax uses exp2
#define QSCALE 0.18033688011112042f
#define XN ((size_t)MTOT*DIM)
#define WN ((size_t)DIM*DIM)

typedef __attribute__((ext_vector_type(8))) short short8;
typedef __attribute__((ext_vector_type(4))) float f32x4;
typedef __attribute__((ext_vector_type(16))) float f32x16;
typedef __attribute__((ext_vector_type(2))) int int2v;

static __device__ __forceinline__ unsigned short bf16rne(float f) {
    unsigned u = __builtin_bit_cast(unsigned, f);
    return (unsigned short)((u + 0x7fffu + ((u >> 16) & 1u)) >> 16);
}

// async global->LDS, 16B per lane; LDS dest must be wave-uniform (HW adds lane*16).
static __device__ __forceinline__ void gld16(const void* g, void* l) {
    __builtin_amdgcn_global_load_lds((const __attribute__((address_space(1))) void*)g,
                                     (__attribute__((address_space(3))) void*)l, 16, 0, 0);
}

static __device__ __forceinline__ f32x16 mfma32(short8 a, short8 b, f32x16 c) {
    return __builtin_amdgcn_mfma_f32_32x32x16_bf16(a, b, c, 0, 0, 0);
}

// ---------------- fused f32 -> bf16 convert of x + 4 weights ----------------
__global__ __launch_bounds__(256)
void prep(const float* __restrict__ x, const float* __restrict__ wq, const float* __restrict__ wk,
          const float* __restrict__ wv, const float* __restrict__ wo, unsigned short* __restrict__ dst)
{
    const size_t i = ((size_t)blockIdx.x*256 + threadIdx.x)*8;
    const float* s; size_t o;
    if (i < XN)           { s = x;  o = i; }
    else if (i < XN+WN)   { s = wq; o = i - XN; }
    else if (i < XN+2*WN) { s = wk; o = i - XN - WN; }
    else if (i < XN+3*WN) { s = wv; o = i - XN - 2*WN; }
    else                  { s = wo; o = i - XN - 3*WN; }
    float4 a = *(const float4*)(s + o);
    float4 b = *(const float4*)(s + o + 4);
    uint4 w;
    w.x = (unsigned)bf16rne(a.x) | ((unsigned)bf16rne(a.y) << 16);
    w.y = (unsigned)bf16rne(a.z) | ((unsigned)bf16rne(a.w) << 16);
    w.z = (unsigned)bf16rne(b.x) | ((unsigned)bf16rne(b.y) << 16);
    w.w = (unsigned)bf16rne(b.z) | ((unsigned)bf16rne(b.w) << 16);
    *(uint4*)&dst[i] = w;
}

// ---------------- fused QKV bf16 GEMM, counted-vmcnt pipeline, 3 blocks/CU ----------------
// 128x128 tile, BK=32, 256 thr (4 waves 2x2), wave tile 64x64. r11-proven main loop.
// Q (widx==0): row-major epilogue. K/V (widx==1/2): one-shot LDS-repack epilogue ->
// attention-fragment-linear Kp/Vp with CONTIGUOUS global stores.
__global__ __launch_bounds__(256)
void gemm_qkv(const unsigned short* __restrict__ A,
              const unsigned short* __restrict__ W0, const unsigned short* __restrict__ W1,
              const unsigned short* __restrict__ W2,
              const float* __restrict__ b0, const float* __restrict__ b1, const float* __restrict__ b2,
              unsigned short* __restrict__ o0, unsigned short* __restrict__ o1, unsigned short* __restrict__ o2)
{
    __shared__ __align__(16) unsigned short smem[24576];   // 48 KB: As[3]|Bs[3] ring; epilogue tile
    #define AS(s) (smem + (s)*4096)
    #define BS(s) (smem + 12288 + (s)*4096)
    const int t = threadIdx.x, wid = t >> 6, lane = t & 63;
    const int lr = lane & 15, lg = lane >> 4;
    const int bid = blockIdx.y * 24 + blockIdx.x;
    const int swz = (bid & 7) * 96 + (bid >> 3);
    const int sx = swz % 24, sy = swz / 24;
    const int widx = sx >> 3;
    const int n0 = (sx & 7) << 7;
    const int m0 = sy << 7;
    const unsigned short* W = widx == 0 ? W0 : (widx == 1 ? W1 : W2);
    const float* bias        = widx == 0 ? b0 : (widx == 1 ? b1 : b2);

    const int wm = wid >> 1, wn = wid & 1;
    const int f0 = 2*wid, f1 = f0 + 1;
    const unsigned short* Ag0 = A + (size_t)(m0 + f0*16 + lr)*DIM + lg*8;
    const unsigned short* Ag1 = A + (size_t)(m0 + f1*16 + lr)*DIM + lg*8;
    const unsigned short* Bg0 = W + (size_t)(n0 + f0*16 + lr)*DIM + lg*8;
    const unsigned short* Bg1 = W + (size_t)(n0 + f1*16 + lr)*DIM + lg*8;

    auto stage = [&](int tt, int slot) {
        const int ko = tt * 32;
        gld16(Ag0 + ko, AS(slot) + f0*512); gld16(Ag1 + ko, AS(slot) + f1*512);
        gld16(Bg0 + ko, BS(slot) + f0*512); gld16(Bg1 + ko, BS(slot) + f1*512);
    };

    f32x4 acc[4][4] = {};
    stage(0, 0); stage(1, 1);
    int c0 = 0, c1 = 1, c2 = 2;

    for (int it = 0; it < DIM/32; ++it) {
        if (it < DIM/32 - 2) { asm volatile("s_waitcnt vmcnt(4)" ::: "memory"); }
        else                 { asm volatile("s_waitcnt vmcnt(0)" ::: "memory"); }
        __builtin_amdgcn_s_barrier();
        short8 af[4], bf[4];
        #pragma unroll
        for (int i = 0; i < 4; ++i) af[i] = *(const short8*)(AS(c0) + (wm*4+i)*512 + lane*8);
        #pragma unroll
        for (int i = 0; i < 4; ++i) bf[i] = *(const short8*)(BS(c0) + (wn*4+i)*512 + lane*8);
        if (it + 2 < DIM/32) stage(it + 2, c2);
        __builtin_amdgcn_s_setprio(1);
        #pragma unroll
        for (int mb = 0; mb < 4; ++mb)
            #pragma unroll
            for (int nb = 0; nb < 4; ++nb)
                acc[mb][nb] = __builtin_amdgcn_mfma_f32_16x16x32_bf16(af[mb], bf[nb], acc[mb][nb], 0, 0, 0);
        __builtin_amdgcn_s_setprio(0);
        const int tmp = c0; c0 = c1; c1 = c2; c2 = tmp;
    }

    if (widx == 0) {
        #pragma unroll
        for (int nb = 0; nb < 4; ++nb) {
            const int col = n0 + wn*64 + nb*16 + lr;
            const float bv = bias[col];
            #pragma unroll
            for (int mb = 0; mb < 4; ++mb) {
                #pragma unroll
                for (int j = 0; j < 4; ++j) {
                    const int row = m0 + wm*64 + mb*16 + lg*4 + j;
                    o0[(size_t)row*DIM + col] = bf16rne((acc[mb][nb][j] + bv) * QSCALE);
                }
            }
        }
    } else {
        // K/V: acc -> LDS tile[128][136], then repack fragment-linear, contiguous stores
        unsigned short* outp = (widx == 1) ? o1 : o2;
        const int isV = (widx == 2);
        __syncthreads();
        unsigned short (*tile)[136] = (unsigned short (*)[136])smem;
        #pragma unroll
        for (int nb = 0; nb < 4; ++nb) {
            const int col = wn*64 + nb*16 + lr;
            const float bv = bias[n0 + col];
            #pragma unroll
            for (int mb = 0; mb < 4; ++mb) {
                #pragma unroll
                for (int j = 0; j < 4; ++j)
                    tile[wm*64 + mb*16 + lg*4 + j][col] = bf16rne(acc[mb][nb][j] + bv);
            }
        }
        __syncthreads();
        const int bb  = m0 >> 11;
        const int kt0 = (m0 & (SEQ-1)) >> 6;
        const int hh0 = n0 >> 6;
        #pragma unroll
        for (int shot = 0; shot < 8; ++shot) {
            const int idx = t + shot*256;
            const int tid = idx >> 9;
            const int fr  = (idx >> 6) & 7;
            const int ln  = idx & 63;
            const int ktl = tid & 1, hhl = tid >> 1;
            short8 ov;
            if (isV) {
                const int r0 = ktl*64 + (fr & 3)*16 + (ln >> 5)*8;
                const int c  = hhl*64 + (fr >> 2)*32 + (ln & 31);
                #pragma unroll
                for (int e = 0; e < 8; ++e) ov[e] = (short)tile[r0 + e][c];
            } else {
                const int r  = ktl*64 + (fr >> 2)*32 + (ln & 31);
                const int cc = hhl*64 + (fr & 3)*16 + (ln >> 5)*8;
                ov = *(const short8*)&tile[r][cc];
            }
            unsigned short* dst = outp
                + ((size_t)((bb*NHEADS + hh0 + hhl)*32 + kt0 + ktl))*4096 + fr*512 + ln*8;
            *(short8*)dst = ov;
        }
    }
    #undef AS
    #undef BS
}

// ---------------- O-projection GEMM: 64x128 tile, counted-vmcnt, f32 out ----------------
__global__ __launch_bounds__(256)
void gemm_o(const unsigned short* __restrict__ A, const unsigned short* __restrict__ W,
            const float* __restrict__ bias, float* __restrict__ fo)
{
    __shared__ __align__(16) unsigned short As[3][2048];
    __shared__ __align__(16) unsigned short Bs[3][4096];
    const int t = threadIdx.x, wid = t >> 6, lane = t & 63;
    const int lr = lane & 15, lg = lane >> 4;
    const int bid = blockIdx.y * 8 + blockIdx.x;
    const int swz = (bid & 7) * 64 + (bid >> 3);
    const int n0 = (swz & 7) << 7;
    const int m0 = (swz >> 3) << 6;
    const int wm = wid >> 1, wn = wid & 1;

    const int fa = wid;
    const int g0 = 2*wid, g1 = g0 + 1;
    const unsigned short* Ag  = A + (size_t)(m0 + fa*16 + lr)*DIM + lg*8;
    const unsigned short* Bg0 = W + (size_t)(n0 + g0*16 + lr)*DIM + lg*8;
    const unsigned short* Bg1 = W + (size_t)(n0 + g1*16 + lr)*DIM + lg*8;

    auto stage = [&](int tt, int slot) {
        const int ko = tt * 32;
        gld16(Ag + ko, &As[slot][fa*512]);
        gld16(Bg0 + ko, &Bs[slot][g0*512]); gld16(Bg1 + ko, &Bs[slot][g1*512]);
    };

    f32x4 acc[2][4] = {};
    stage(0, 0); stage(1, 1);
    int c0 = 0, c1 = 1, c2 = 2;

    for (int it = 0; it < DIM/32; ++it) {
        if (it < DIM/32 - 2) { asm volatile("s_waitcnt vmcnt(3)" ::: "memory"); }
        else                 { asm volatile("s_waitcnt vmcnt(0)" ::: "memory"); }
        __builtin_amdgcn_s_barrier();
        short8 af[2], bf[4];
        #pragma unroll
        for (int i = 0; i < 2; ++i) af[i] = *(const short8*)&As[c0][(wm*2+i)*512 + lane*8];
        #pragma unroll
        for (int i = 0; i < 4; ++i) bf[i] = *(const short8*)&Bs[c0][(wn*4+i)*512 + lane*8];
        if (it + 2 < DIM/32) stage(it + 2, c2);
        __builtin_amdgcn_s_setprio(1);
        #pragma unroll
        for (int mb = 0; mb < 2; ++mb)
            #pragma unroll
            for (int nb = 0; nb < 4; ++nb)
                acc[mb][nb] = __builtin_amdgcn_mfma_f32_16x16x32_bf16(af[mb], bf[nb], acc[mb][nb], 0, 0, 0);
        __builtin_amdgcn_s_setprio(0);
        const int tmp = c0; c0 = c1; c1 = c2; c2 = tmp;
    }

    #pragma unroll
    for (int nb = 0; nb < 4; ++nb) {
        const int col = n0 + wn*64 + nb*16 + lr;
        const float bv = bias[col];
        #pragma unroll
        for (int mb = 0; mb < 2; ++mb) {
            #pragma unroll
            for (int j = 0; j < 4; ++j) {
                const int row = m0 + wm*32 + mb*16 + lg*4 + j;
                fo[(size_t)row*DIM + col] = acc[mb][nb][j] + bv;
            }
        }
    }
}

// ---------------- MFMA flash attention: 64 q-rows/wave (2x LDS-read reuse) ----------------
// Attn is LDS-read-port bound (r15: 16 waves x 32 ds_read_b128 x 12cyc = 98% of window
// wall). Fix: each wave covers TWO 32-row q-halves; every kf/vf LDS read feeds 4 MFMAs
// instead of 2 -> ds_read per MFMA halves. 2 waves x 64 rows = 128 rows/block,
// grid (16,32) = 512 blocks = 2 blocks/CU (decorrelated blocks hide stalls).
// Same 2-tile window + counted vmcnt (8 gld16/stage -> vmcnt(8)).
struct PA { short8 p[4]; };

static __device__ __forceinline__ PA softmax_pack(const f32x16& s0, const f32x16& s1, float& lsum) {
    float rsum = 0.f;
    unsigned pw0[4][2], pw1[4][2];
    #pragma unroll
    for (int r1 = 0; r1 < 4; ++r1)
        #pragma unroll
        for (int tt = 0; tt < 2; ++tt) {
            float pa_ = __builtin_amdgcn_exp2f(s0[4*r1+2*tt]);
            float pb_ = __builtin_amdgcn_exp2f(s0[4*r1+2*tt+1]);
            float pc_ = __builtin_amdgcn_exp2f(s1[4*r1+2*tt]);
            float pd_ = __builtin_amdgcn_exp2f(s1[4*r1+2*tt+1]);
            rsum += (pa_ + pb_) + (pc_ + pd_);
            asm("v_cvt_pk_bf16_f32 %0, %1, %2" : "=v"(pw0[r1][tt]) : "v"(pa_), "v"(pb_));
            asm("v_cvt_pk_bf16_f32 %0, %1, %2" : "=v"(pw1[r1][tt]) : "v"(pc_), "v"(pd_));
        }
    rsum += __shfl_xor(rsum, 32);
    lsum += rsum;
    PA r;
    #pragma unroll
    for (int ss = 0; ss < 4; ++ss) {
        union { short8 s8; unsigned u[4]; } pu;
        #pragma unroll
        for (int tt = 0; tt < 2; ++tt) {
            const unsigned a = (ss >> 1) ? pw1[2*(ss&1)][tt]   : pw0[2*(ss&1)][tt];
            const unsigned b = (ss >> 1) ? pw1[2*(ss&1)+1][tt] : pw0[2*(ss&1)+1][tt];
            int2v sw = __builtin_amdgcn_permlane32_swap((int)a, (int)b, false, false);
            pu.u[tt]     = (unsigned)sw[0];
            pu.u[2 + tt] = (unsigned)sw[1];
        }
        r.p[ss] = pu.s8;
    }
    return r;
}

__global__ __launch_bounds__(128)
void attn_mfma2(const unsigned short* __restrict__ Q, const unsigned short* __restrict__ Kp,
                const unsigned short* __restrict__ Vp, unsigned short* __restrict__ O)
{
    __shared__ __align__(16) unsigned short Ks[4][4096];
    __shared__ __align__(16) unsigned short Vs[4][4096];
    const int t = threadIdx.x, wid = t >> 6, lane = t & 63;   // wid 0..1
    const int l31 = lane & 31, h = lane >> 5;
    // grid (16, 32) = 512 blocks; swizzle: XCD c gets heads 4c..4c+3
    const int bid = blockIdx.y * 16 + blockIdx.x;
    const int swz = (bid & 7) * 64 + (bid >> 3);
    const int qt = swz & 15, bh = swz >> 4;
    const int b = bh >> 4, hh = bh & 15;
    const size_t qkbase = (size_t)b*SEQ*DIM + (size_t)hh*HDIM;
    const unsigned short* Qb = Q + qkbase;
    unsigned short*       Ob = O + qkbase;
    const int q0 = qt*128 + wid*64;   // wave owns q-rows q0..q0+63 (halves A/B)

    short8 qfA[4], qfB[4];
    #pragma unroll
    for (int ds = 0; ds < 4; ++ds) {
        qfA[ds] = *(const short8*)&Qb[(size_t)(q0 + l31)*DIM + ds*16 + h*8];
        qfB[ds] = *(const short8*)&Qb[(size_t)(q0 + 32 + l31)*DIM + ds*16 + h*8];
    }

    // wave stages K frags {4wid..4wid+3}, V frags {4wid..4wid+3} (1KB contiguous each)
    const unsigned short* Kg = Kp + (size_t)bh*32*4096 + 4*wid*512 + lane*8;
    const unsigned short* Vg = Vp + (size_t)bh*32*4096 + 4*wid*512 + lane*8;

    auto stage = [&](int tn) {   // tn < 32; 8 gld16 per wave
        const size_t ko = (size_t)tn * 4096;
        const int bb = tn & 3;
        #pragma unroll
        for (int i = 0; i < 4; ++i) {
            gld16(Kg + ko + i*512, &Ks[bb][(4*wid + i)*512]);
            gld16(Vg + ko + i*512, &Vs[bb][(4*wid + i)*512]);
        }
    };

    f32x16 ctxA0 = {}, ctxA1 = {}, ctxB0 = {}, ctxB1 = {};
    float lsumA = 0.0f, lsumB = 0.0f;

    stage(0); stage(1);   // 16 loads in flight per wave

    const int NW = SEQ/128;
    for (int w = 0; w < NW; ++w) {
        const int t0 = 2*w;
        const int ba = t0 & 3, bb2 = (t0+1) & 3;
        const bool more = (w + 1 < NW);

        // B1: own stage(t0) landed (stage(t0+1)'s 8 loads stay in flight)
        if (more) { asm volatile("s_waitcnt vmcnt(8)" ::: "memory"); }
        else      { asm volatile("s_waitcnt vmcnt(0)" ::: "memory"); }
        __builtin_amdgcn_s_barrier();
        if (more) stage(t0 + 2);

        // QK(t0): each kf read feeds both q-halves
        f32x16 s0A = {}, s1A = {}, s0B = {}, s1B = {};
        __builtin_amdgcn_s_setprio(1);
        #pragma unroll
        for (int ds = 0; ds < 4; ++ds) {
            short8 kf0 = *(const short8*)&Ks[ba][ds*512 + lane*8];
            short8 kf1 = *(const short8*)&Ks[ba][(4+ds)*512 + lane*8];
            s0A = mfma32(kf0, qfA[ds], s0A);
            s1A = mfma32(kf1, qfA[ds], s1A);
            s0B = mfma32(kf0, qfB[ds], s0B);
            s1B = mfma32(kf1, qfB[ds], s1B);
        }
        __builtin_amdgcn_s_setprio(0);

        PA paA = softmax_pack(s0A, s1A, lsumA);
        PA paB = softmax_pack(s0B, s1B, lsumB);

        // B2: own stage(t0+1) landed; gates stage(t0+3)
        if (more) { asm volatile("s_waitcnt vmcnt(8)" ::: "memory"); }
        else      { asm volatile("s_waitcnt vmcnt(0)" ::: "memory"); }
        __builtin_amdgcn_s_barrier();
        if (more) stage(t0 + 3);

        // QK(t1) + PV(t0) interleaved (independent chains)
        f32x16 r0A = {}, r1A = {}, r0B = {}, r1B = {};
        __builtin_amdgcn_s_setprio(1);
        #pragma unroll
        for (int ds = 0; ds < 4; ++ds) {
            short8 kf0 = *(const short8*)&Ks[bb2][ds*512 + lane*8];
            short8 kf1 = *(const short8*)&Ks[bb2][(4+ds)*512 + lane*8];
            r0A = mfma32(kf0, qfA[ds], r0A);
            r1A = mfma32(kf1, qfA[ds], r1A);
            r0B = mfma32(kf0, qfB[ds], r0B);
            r1B = mfma32(kf1, qfB[ds], r1B);
        }
        #pragma unroll
        for (int ss = 0; ss < 4; ++ss) {
            short8 vf0 = *(const short8*)&Vs[ba][ss*512 + lane*8];
            short8 vf1 = *(const short8*)&Vs[ba][(4+ss)*512 + lane*8];
            ctxA0 = mfma32(paA.p[ss], vf0, ctxA0);
            ctxA1 = mfma32(paA.p[ss], vf1, ctxA1);
            ctxB0 = mfma32(paB.p[ss], vf0, ctxB0);
            ctxB1 = mfma32(paB.p[ss], vf1, ctxB1);
        }
        __builtin_amdgcn_s_setprio(0);

        PA pbA = softmax_pack(r0A, r1A, lsumA);
        PA pbB = softmax_pack(r0B, r1B, lsumB);

        // PV(t1)
        __builtin_amdgcn_s_setprio(1);
        #pragma unroll
        for (int ss = 0; ss < 4; ++ss) {
            short8 vf0 = *(const short8*)&Vs[bb2][ss*512 + lane*8];
            short8 vf1 = *(const short8*)&Vs[bb2][(4+ss)*512 + lane*8];
            ctxA0 = mfma32(pbA.p[ss], vf0, ctxA0);
            ctxA1 = mfma32(pbA.p[ss], vf1, ctxA1);
            ctxB0 = mfma32(pbB.p[ss], vf0, ctxB0);
            ctxB1 = mfma32(pbB.p[ss], vf1, ctxB1);
        }
        __builtin_amdgcn_s_setprio(0);
    }

    const float linvA = 1.0f / lsumA;
    const float linvB = 1.0f / lsumB;
    #pragma unroll
    for (int r = 0; r < 16; ++r) {
        const int qrow = (r&3) + 8*(r>>2) + 4*h;
        const float nmA = __shfl(linvA, qrow);
        const float nmB = __shfl(linvB, qrow);
        unsigned short* pA = &Ob[(size_t)(q0 + qrow)*DIM + l31];
        unsigned short* pB = &Ob[(size_t)(q0 + 32 + qrow)*DIM + l31];
        pA[0]  = bf16rne(ctxA0[r] * nmA);
        pA[32] = bf16rne(ctxA1[r] * nmA);
        pB[0]  = bf16rne(ctxB0[r] * nmB);
        pB[32] = bf16rne(ctxB1[r] * nmB);
    }
}

extern "C" void kernel_launch(void* const* d_in, const int* in_sizes, int n_in,
                              void* d_out, int out_size, void* d_ws, size_t ws_size,
                              hipStream_t stream) {
    const float* x  = (const float*)d_in[0];
    const float* wq = (const float*)d_in[1];
    const float* bq = (const float*)d_in[2];
    const float* wk = (const float*)d_in[3];
    const float* bk = (const float*)d_in[4];
    const float* wv = (const float*)d_in[5];
    const float* bv = (const float*)d_in[6];
    const float* wo = (const float*)d_in[7];
    const float* bo = (const float*)d_in[8];
    float* out = (float*)d_out;

    // ws (ushort): Xb 4M | Wq 1M | Wk 1M | Wv 1M | Wo 1M | Qb 4M | Kpb 4M | Vpb 4M = 40 MB
    // Cb aliases Xb (x dead after gemm_qkv).
    unsigned short* Xb  = (unsigned short*)d_ws;
    unsigned short* Wqb = Xb  + XN;
    unsigned short* Wkb = Wqb + WN;
    unsigned short* Wvb = Wkb + WN;
    unsigned short* Wob = Wvb + WN;
    unsigned short* Qb  = Wob + WN;
    unsigned short* Kpb = Qb  + XN;
    unsigned short* Vpb = Kpb + XN;
    unsigned short* Cb  = Xb;

    prep<<<4096, 256, 0, stream>>>(x, wq, wk, wv, wo, Xb);

    // K/V written directly in fragment-linear layout (pack fused into epilogue)
    gemm_qkv<<<dim3(24, 32), 256, 0, stream>>>(Xb, Wqb, Wkb, Wvb, bq, bk, bv, Qb, Kpb, Vpb);

    attn_mfma2<<<dim3(16, BATCH*NHEADS), 128, 0, stream>>>(Qb, Kpb, Vpb, Cb);

    gemm_o<<<dim3(8, 64), 256, 0, stream>>>(Cb, Wob, bo, out);
}

// Round 17
// 127.550 us; speedup vs baseline: 1.0825x; 1.0825x over previous
//
#include <hip/hip_runtime.h>

#define DIM 1024
#define NHEADS 16
#define HDIM 64
#define BATCH 2
#define SEQ 2048
#define MTOT (BATCH*SEQ)
// 1/sqrt(64) * log2(e), folded into Q so softmax uses exp2
#define QSCALE 0.18033688011112042f
#define XN ((size_t)MTOT*DIM)
#define WN ((size_t)DIM*DIM)

typedef __attribute__((ext_vector_type(8))) short short8;
typedef __attribute__((ext_vector_type(4))) float f32x4;
typedef __attribute__((ext_vector_type(16))) float f32x16;
typedef __attribute__((ext_vector_type(2))) int int2v;

static __device__ __forceinline__ unsigned short bf16rne(float f) {
    unsigned u = __builtin_bit_cast(unsigned, f);
    return (unsigned short)((u + 0x7fffu + ((u >> 16) & 1u)) >> 16);
}

// async global->LDS, 16B per lane; LDS dest must be wave-uniform (HW adds lane*16).
static __device__ __forceinline__ void gld16(const void* g, void* l) {
    __builtin_amdgcn_global_load_lds((const __attribute__((address_space(1))) void*)g,
                                     (__attribute__((address_space(3))) void*)l, 16, 0, 0);
}

static __device__ __forceinline__ f32x16 mfma32(short8 a, short8 b, f32x16 c) {
    return __builtin_amdgcn_mfma_f32_32x32x16_bf16(a, b, c, 0, 0, 0);
}

// ---------------- fused f32 -> bf16 convert of x + 4 weights ----------------
__global__ __launch_bounds__(256)
void prep(const float* __restrict__ x, const float* __restrict__ wq, const float* __restrict__ wk,
          const float* __restrict__ wv, const float* __restrict__ wo, unsigned short* __restrict__ dst)
{
    const size_t i = ((size_t)blockIdx.x*256 + threadIdx.x)*8;
    const float* s; size_t o;
    if (i < XN)           { s = x;  o = i; }
    else if (i < XN+WN)   { s = wq; o = i - XN; }
    else if (i < XN+2*WN) { s = wk; o = i - XN - WN; }
    else if (i < XN+3*WN) { s = wv; o = i - XN - 2*WN; }
    else                  { s = wo; o = i - XN - 3*WN; }
    float4 a = *(const float4*)(s + o);
    float4 b = *(const float4*)(s + o + 4);
    uint4 w;
    w.x = (unsigned)bf16rne(a.x) | ((unsigned)bf16rne(a.y) << 16);
    w.y = (unsigned)bf16rne(a.z) | ((unsigned)bf16rne(a.w) << 16);
    w.z = (unsigned)bf16rne(b.x) | ((unsigned)bf16rne(b.y) << 16);
    w.w = (unsigned)bf16rne(b.z) | ((unsigned)bf16rne(b.w) << 16);
    *(uint4*)&dst[i] = w;
}

// ---------------- fused QKV bf16 GEMM, counted-vmcnt pipeline, 3 blocks/CU ----------------
// 128x128 tile, BK=32, 256 thr (4 waves 2x2), wave tile 64x64. r11-proven main loop.
// Q (widx==0): row-major epilogue. K/V (widx==1/2): one-shot LDS-repack epilogue ->
// attention-fragment-linear Kp/Vp with CONTIGUOUS global stores.
__global__ __launch_bounds__(256)
void gemm_qkv(const unsigned short* __restrict__ A,
              const unsigned short* __restrict__ W0, const unsigned short* __restrict__ W1,
              const unsigned short* __restrict__ W2,
              const float* __restrict__ b0, const float* __restrict__ b1, const float* __restrict__ b2,
              unsigned short* __restrict__ o0, unsigned short* __restrict__ o1, unsigned short* __restrict__ o2)
{
    __shared__ __align__(16) unsigned short smem[24576];   // 48 KB: As[3]|Bs[3] ring; epilogue tile
    #define AS(s) (smem + (s)*4096)
    #define BS(s) (smem + 12288 + (s)*4096)
    const int t = threadIdx.x, wid = t >> 6, lane = t & 63;
    const int lr = lane & 15, lg = lane >> 4;
    const int bid = blockIdx.y * 24 + blockIdx.x;
    const int swz = (bid & 7) * 96 + (bid >> 3);
    const int sx = swz % 24, sy = swz / 24;
    const int widx = sx >> 3;
    const int n0 = (sx & 7) << 7;
    const int m0 = sy << 7;
    const unsigned short* W = widx == 0 ? W0 : (widx == 1 ? W1 : W2);
    const float* bias        = widx == 0 ? b0 : (widx == 1 ? b1 : b2);

    const int wm = wid >> 1, wn = wid & 1;
    const int f0 = 2*wid, f1 = f0 + 1;
    const unsigned short* Ag0 = A + (size_t)(m0 + f0*16 + lr)*DIM + lg*8;
    const unsigned short* Ag1 = A + (size_t)(m0 + f1*16 + lr)*DIM + lg*8;
    const unsigned short* Bg0 = W + (size_t)(n0 + f0*16 + lr)*DIM + lg*8;
    const unsigned short* Bg1 = W + (size_t)(n0 + f1*16 + lr)*DIM + lg*8;

    auto stage = [&](int tt, int slot) {
        const int ko = tt * 32;
        gld16(Ag0 + ko, AS(slot) + f0*512); gld16(Ag1 + ko, AS(slot) + f1*512);
        gld16(Bg0 + ko, BS(slot) + f0*512); gld16(Bg1 + ko, BS(slot) + f1*512);
    };

    f32x4 acc[4][4] = {};
    stage(0, 0); stage(1, 1);
    int c0 = 0, c1 = 1, c2 = 2;

    for (int it = 0; it < DIM/32; ++it) {
        if (it < DIM/32 - 2) { asm volatile("s_waitcnt vmcnt(4)" ::: "memory"); }
        else                 { asm volatile("s_waitcnt vmcnt(0)" ::: "memory"); }
        __builtin_amdgcn_s_barrier();
        short8 af[4], bf[4];
        #pragma unroll
        for (int i = 0; i < 4; ++i) af[i] = *(const short8*)(AS(c0) + (wm*4+i)*512 + lane*8);
        #pragma unroll
        for (int i = 0; i < 4; ++i) bf[i] = *(const short8*)(BS(c0) + (wn*4+i)*512 + lane*8);
        if (it + 2 < DIM/32) stage(it + 2, c2);
        __builtin_amdgcn_s_setprio(1);
        #pragma unroll
        for (int mb = 0; mb < 4; ++mb)
            #pragma unroll
            for (int nb = 0; nb < 4; ++nb)
                acc[mb][nb] = __builtin_amdgcn_mfma_f32_16x16x32_bf16(af[mb], bf[nb], acc[mb][nb], 0, 0, 0);
        __builtin_amdgcn_s_setprio(0);
        const int tmp = c0; c0 = c1; c1 = c2; c2 = tmp;
    }

    if (widx == 0) {
        #pragma unroll
        for (int nb = 0; nb < 4; ++nb) {
            const int col = n0 + wn*64 + nb*16 + lr;
            const float bv = bias[col];
            #pragma unroll
            for (int mb = 0; mb < 4; ++mb) {
                #pragma unroll
                for (int j = 0; j < 4; ++j) {
                    const int row = m0 + wm*64 + mb*16 + lg*4 + j;
                    o0[(size_t)row*DIM + col] = bf16rne((acc[mb][nb][j] + bv) * QSCALE);
                }
            }
        }
    } else {
        // K/V: acc -> LDS tile[128][136], then repack fragment-linear, contiguous stores
        unsigned short* outp = (widx == 1) ? o1 : o2;
        const int isV = (widx == 2);
        __syncthreads();
        unsigned short (*tile)[136] = (unsigned short (*)[136])smem;
        #pragma unroll
        for (int nb = 0; nb < 4; ++nb) {
            const int col = wn*64 + nb*16 + lr;
            const float bv = bias[n0 + col];
            #pragma unroll
            for (int mb = 0; mb < 4; ++mb) {
                #pragma unroll
                for (int j = 0; j < 4; ++j)
                    tile[wm*64 + mb*16 + lg*4 + j][col] = bf16rne(acc[mb][nb][j] + bv);
            }
        }
        __syncthreads();
        const int bb  = m0 >> 11;
        const int kt0 = (m0 & (SEQ-1)) >> 6;
        const int hh0 = n0 >> 6;
        #pragma unroll
        for (int shot = 0; shot < 8; ++shot) {
            const int idx = t + shot*256;
            const int tid = idx >> 9;
            const int fr  = (idx >> 6) & 7;
            const int ln  = idx & 63;
            const int ktl = tid & 1, hhl = tid >> 1;
            short8 ov;
            if (isV) {
                const int r0 = ktl*64 + (fr & 3)*16 + (ln >> 5)*8;
                const int c  = hhl*64 + (fr >> 2)*32 + (ln & 31);
                #pragma unroll
                for (int e = 0; e < 8; ++e) ov[e] = (short)tile[r0 + e][c];
            } else {
                const int r  = ktl*64 + (fr >> 2)*32 + (ln & 31);
                const int cc = hhl*64 + (fr & 3)*16 + (ln >> 5)*8;
                ov = *(const short8*)&tile[r][cc];
            }
            unsigned short* dst = outp
                + ((size_t)((bb*NHEADS + hh0 + hhl)*32 + kt0 + ktl))*4096 + fr*512 + ln*8;
            *(short8*)dst = ov;
        }
    }
    #undef AS
    #undef BS
}

// ---------------- O-projection GEMM: 64x128 tile, counted-vmcnt, f32 out ----------------
__global__ __launch_bounds__(256)
void gemm_o(const unsigned short* __restrict__ A, const unsigned short* __restrict__ W,
            const float* __restrict__ bias, float* __restrict__ fo)
{
    __shared__ __align__(16) unsigned short As[3][2048];
    __shared__ __align__(16) unsigned short Bs[3][4096];
    const int t = threadIdx.x, wid = t >> 6, lane = t & 63;
    const int lr = lane & 15, lg = lane >> 4;
    const int bid = blockIdx.y * 8 + blockIdx.x;
    const int swz = (bid & 7) * 64 + (bid >> 3);
    const int n0 = (swz & 7) << 7;
    const int m0 = (swz >> 3) << 6;
    const int wm = wid >> 1, wn = wid & 1;

    const int fa = wid;
    const int g0 = 2*wid, g1 = g0 + 1;
    const unsigned short* Ag  = A + (size_t)(m0 + fa*16 + lr)*DIM + lg*8;
    const unsigned short* Bg0 = W + (size_t)(n0 + g0*16 + lr)*DIM + lg*8;
    const unsigned short* Bg1 = W + (size_t)(n0 + g1*16 + lr)*DIM + lg*8;

    auto stage = [&](int tt, int slot) {
        const int ko = tt * 32;
        gld16(Ag + ko, &As[slot][fa*512]);
        gld16(Bg0 + ko, &Bs[slot][g0*512]); gld16(Bg1 + ko, &Bs[slot][g1*512]);
    };

    f32x4 acc[2][4] = {};
    stage(0, 0); stage(1, 1);
    int c0 = 0, c1 = 1, c2 = 2;

    for (int it = 0; it < DIM/32; ++it) {
        if (it < DIM/32 - 2) { asm volatile("s_waitcnt vmcnt(3)" ::: "memory"); }
        else                 { asm volatile("s_waitcnt vmcnt(0)" ::: "memory"); }
        __builtin_amdgcn_s_barrier();
        short8 af[2], bf[4];
        #pragma unroll
        for (int i = 0; i < 2; ++i) af[i] = *(const short8*)&As[c0][(wm*2+i)*512 + lane*8];
        #pragma unroll
        for (int i = 0; i < 4; ++i) bf[i] = *(const short8*)&Bs[c0][(wn*4+i)*512 + lane*8];
        if (it + 2 < DIM/32) stage(it + 2, c2);
        __builtin_amdgcn_s_setprio(1);
        #pragma unroll
        for (int mb = 0; mb < 2; ++mb)
            #pragma unroll
            for (int nb = 0; nb < 4; ++nb)
                acc[mb][nb] = __builtin_amdgcn_mfma_f32_16x16x32_bf16(af[mb], bf[nb], acc[mb][nb], 0, 0, 0);
        __builtin_amdgcn_s_setprio(0);
        const int tmp = c0; c0 = c1; c1 = c2; c2 = tmp;
    }

    #pragma unroll
    for (int nb = 0; nb < 4; ++nb) {
        const int col = n0 + wn*64 + nb*16 + lr;
        const float bv = bias[col];
        #pragma unroll
        for (int mb = 0; mb < 2; ++mb) {
            #pragma unroll
            for (int j = 0; j < 4; ++j) {
                const int row = m0 + wm*32 + mb*16 + lg*4 + j;
                fo[(size_t)row*DIM + col] = acc[mb][nb][j] + bv;
            }
        }
    }
}

// ---------------- MFMA flash attention: key-split waves + in-LDS combine ----------------
// 8 waves = 4 q-groups (64 rows, halves A/B) x 2 key-halves. Each wave reads only its
// key-half's 4 K-frags + 4 V-frags per tile -> 16 ds_read/window/wave (r15: 32) at
// 2048 total waves (8/CU). No online max -> ctx/lsum partials are pure sums; combine is
// one in-LDS round-trip at kernel end (ring LDS aliased after barrier). 256 blocks,
// 66 KB LDS. Same r15-proven 2-tile window + counted vmcnt(2) staging.
struct PA2 { short8 p[2]; };

static __device__ __forceinline__ PA2 smpack32(const f32x16& s0, float& lsum) {
    float rsum = 0.f;
    unsigned pw0[4][2];
    #pragma unroll
    for (int r1 = 0; r1 < 4; ++r1)
        #pragma unroll
        for (int tt = 0; tt < 2; ++tt) {
            float pa_ = __builtin_amdgcn_exp2f(s0[4*r1+2*tt]);
            float pb_ = __builtin_amdgcn_exp2f(s0[4*r1+2*tt+1]);
            rsum += pa_ + pb_;
            asm("v_cvt_pk_bf16_f32 %0, %1, %2" : "=v"(pw0[r1][tt]) : "v"(pa_), "v"(pb_));
        }
    rsum += __shfl_xor(rsum, 32);
    lsum += rsum;
    PA2 r;
    #pragma unroll
    for (int ss = 0; ss < 2; ++ss) {
        union { short8 s8; unsigned u[4]; } pu;
        #pragma unroll
        for (int tt = 0; tt < 2; ++tt) {
            int2v sw = __builtin_amdgcn_permlane32_swap(
                (int)pw0[2*ss][tt], (int)pw0[2*ss+1][tt], false, false);
            pu.u[tt]     = (unsigned)sw[0];
            pu.u[2 + tt] = (unsigned)sw[1];
        }
        r.p[ss] = pu.s8;
    }
    return r;
}

__global__ __launch_bounds__(512)
void attn_mfma3(const unsigned short* __restrict__ Q, const unsigned short* __restrict__ Kp,
                const unsigned short* __restrict__ Vp, unsigned short* __restrict__ O)
{
    // 66 KB: ring Ks[4][4096]|Vs[4][4096] (64 KB); combine area cb aliases smem after
    // the post-loop barrier (ring dead). cb layout: [4 groups][64 lanes][66 f32].
    __shared__ __align__(16) unsigned char smem[67584];
    unsigned short* KsB = (unsigned short*)smem;             // slot stride 4096 ushorts
    unsigned short* VsB = (unsigned short*)(smem + 32768);
    float* cb = (float*)smem;

    const int t = threadIdx.x, wid = t >> 6, lane = t & 63;  // wid 0..7
    const int l31 = lane & 31, h = lane >> 5;
    const int g = wid >> 1;    // q-group (64 rows)
    const int kh = wid & 1;    // key half (32 of 64 keys per tile)
    // grid (8, 32) = 256 blocks; swizzle: XCD c gets heads 4c..4c+3
    const int bid = blockIdx.y * 8 + blockIdx.x;
    const int swz = (bid & 7) * 32 + (bid >> 3);
    const int qt = swz & 7, bh = swz >> 3;
    const int b = bh >> 4, hh = bh & 15;
    const size_t qkbase = (size_t)b*SEQ*DIM + (size_t)hh*HDIM;
    const unsigned short* Qb = Q + qkbase;
    unsigned short*       Ob = O + qkbase;
    const int q0 = qt*256 + g*64;   // group owns q-rows q0..q0+63 (halves A/B)

    short8 qfA[4], qfB[4];
    #pragma unroll
    for (int ds = 0; ds < 4; ++ds) {
        qfA[ds] = *(const short8*)&Qb[(size_t)(q0 + l31)*DIM + ds*16 + h*8];
        qfB[ds] = *(const short8*)&Qb[(size_t)(q0 + 32 + l31)*DIM + ds*16 + h*8];
    }

    // wave stages K frag wid, V frag wid (1 KB contiguous each)
    const unsigned short* Kg = Kp + (size_t)bh*32*4096 + wid*512 + lane*8;
    const unsigned short* Vg = Vp + (size_t)bh*32*4096 + wid*512 + lane*8;

    auto stage = [&](int tn) {   // tn < 32; 2 gld16 per wave
        const size_t ko = (size_t)tn * 4096;
        const int bb = tn & 3;
        gld16(Kg + ko, KsB + bb*4096 + wid*512);
        gld16(Vg + ko, VsB + bb*4096 + wid*512);
    };

    f32x16 ctxA0 = {}, ctxA1 = {}, ctxB0 = {}, ctxB1 = {};
    float lsumA = 0.0f, lsumB = 0.0f;

    stage(0); stage(1);

    const int NW = SEQ/128;
    for (int w = 0; w < NW; ++w) {
        const int t0 = 2*w;
        const int ba = t0 & 3, bb2 = (t0+1) & 3;
        const bool more = (w + 1 < NW);

        if (more) { asm volatile("s_waitcnt vmcnt(2)" ::: "memory"); }
        else      { asm volatile("s_waitcnt vmcnt(0)" ::: "memory"); }
        __builtin_amdgcn_s_barrier();
        if (more) stage(t0 + 2);

        // QK(t0): only this wave's key-half frags (4kh..4kh+3); kf feeds both q-halves
        f32x16 sA = {}, sB = {};
        __builtin_amdgcn_s_setprio(1);
        #pragma unroll
        for (int ds = 0; ds < 4; ++ds) {
            short8 kf = *(const short8*)(KsB + ba*4096 + (4*kh + ds)*512 + lane*8);
            sA = mfma32(kf, qfA[ds], sA);
            sB = mfma32(kf, qfB[ds], sB);
        }
        __builtin_amdgcn_s_setprio(0);

        PA2 paA = smpack32(sA, lsumA);
        PA2 paB = smpack32(sB, lsumB);

        if (more) { asm volatile("s_waitcnt vmcnt(2)" ::: "memory"); }
        else      { asm volatile("s_waitcnt vmcnt(0)" ::: "memory"); }
        __builtin_amdgcn_s_barrier();
        if (more) stage(t0 + 3);

        // QK(t1) + PV(t0) interleaved
        f32x16 rA = {}, rB = {};
        __builtin_amdgcn_s_setprio(1);
        #pragma unroll
        for (int ds = 0; ds < 4; ++ds) {
            short8 kf = *(const short8*)(KsB + bb2*4096 + (4*kh + ds)*512 + lane*8);
            rA = mfma32(kf, qfA[ds], rA);
            rB = mfma32(kf, qfB[ds], rB);
        }
        #pragma unroll
        for (int ls = 0; ls < 2; ++ls) {
            short8 vf0 = *(const short8*)(VsB + ba*4096 + (2*kh + ls)*512 + lane*8);
            short8 vf1 = *(const short8*)(VsB + ba*4096 + (4 + 2*kh + ls)*512 + lane*8);
            ctxA0 = mfma32(paA.p[ls], vf0, ctxA0);
            ctxA1 = mfma32(paA.p[ls], vf1, ctxA1);
            ctxB0 = mfma32(paB.p[ls], vf0, ctxB0);
            ctxB1 = mfma32(paB.p[ls], vf1, ctxB1);
        }
        __builtin_amdgcn_s_setprio(0);

        PA2 pbA = smpack32(rA, lsumA);
        PA2 pbB = smpack32(rB, lsumB);

        // PV(t1)
        __builtin_amdgcn_s_setprio(1);
        #pragma unroll
        for (int ls = 0; ls < 2; ++ls) {
            short8 vf0 = *(const short8*)(VsB + bb2*4096 + (2*kh + ls)*512 + lane*8);
            short8 vf1 = *(const short8*)(VsB + bb2*4096 + (4 + 2*kh + ls)*512 + lane*8);
            ctxA0 = mfma32(pbA.p[ls], vf0, ctxA0);
            ctxA1 = mfma32(pbA.p[ls], vf1, ctxA1);
            ctxB0 = mfma32(pbB.p[ls], vf0, ctxB0);
            ctxB1 = mfma32(pbB.p[ls], vf1, ctxB1);
        }
        __builtin_amdgcn_s_setprio(0);
    }

    // in-LDS combine of the two key-halves (ring is dead after this barrier)
    __syncthreads();
    if (kh == 1) {
        float* dst = cb + ((size_t)g*64 + lane)*66;
        #pragma unroll
        for (int r = 0; r < 16; ++r) {
            dst[r]      = ctxA0[r];
            dst[16 + r] = ctxA1[r];
            dst[32 + r] = ctxB0[r];
            dst[48 + r] = ctxB1[r];
        }
        dst[64] = lsumA;
        dst[65] = lsumB;
    }
    __syncthreads();
    if (kh == 0) {
        const float* src = cb + ((size_t)g*64 + lane)*66;
        #pragma unroll
        for (int r = 0; r < 16; ++r) {
            ctxA0[r] += src[r];
            ctxA1[r] += src[16 + r];
            ctxB0[r] += src[32 + r];
            ctxB1[r] += src[48 + r];
        }
        lsumA += src[64];
        lsumB += src[65];

        const float linvA = 1.0f / lsumA;
        const float linvB = 1.0f / lsumB;
        #pragma unroll
        for (int r = 0; r < 16; ++r) {
            const int qrow = (r&3) + 8*(r>>2) + 4*h;
            const float nmA = __shfl(linvA, qrow);
            const float nmB = __shfl(linvB, qrow);
            unsigned short* pA = &Ob[(size_t)(q0 + qrow)*DIM + l31];
            unsigned short* pB = &Ob[(size_t)(q0 + 32 + qrow)*DIM + l31];
            pA[0]  = bf16rne(ctxA0[r] * nmA);
            pA[32] = bf16rne(ctxA1[r] * nmA);
            pB[0]  = bf16rne(ctxB0[r] * nmB);
            pB[32] = bf16rne(ctxB1[r] * nmB);
        }
    }
}

extern "C" void kernel_launch(void* const* d_in, const int* in_sizes, int n_in,
                              void* d_out, int out_size, void* d_ws, size_t ws_size,
                              hipStream_t stream) {
    const float* x  = (const float*)d_in[0];
    const float* wq = (const float*)d_in[1];
    const float* bq = (const float*)d_in[2];
    const float* wk = (const float*)d_in[3];
    const float* bk = (const float*)d_in[4];
    const float* wv = (const float*)d_in[5];
    const float* bv = (const float*)d_in[6];
    const float* wo = (const float*)d_in[7];
    const float* bo = (const float*)d_in[8];
    float* out = (float*)d_out;

    // ws (ushort): Xb 4M | Wq 1M | Wk 1M | Wv 1M | Wo 1M | Qb 4M | Kpb 4M | Vpb 4M = 40 MB
    // Cb aliases Xb (x dead after gemm_qkv).
    unsigned short* Xb  = (unsigned short*)d_ws;
    unsigned short* Wqb = Xb  + XN;
    unsigned short* Wkb = Wqb + WN;
    unsigned short* Wvb = Wkb + WN;
    unsigned short* Wob = Wvb + WN;
    unsigned short* Qb  = Wob + WN;
    unsigned short* Kpb = Qb  + XN;
    unsigned short* Vpb = Kpb + XN;
    unsigned short* Cb  = Xb;

    prep<<<4096, 256, 0, stream>>>(x, wq, wk, wv, wo, Xb);

    // K/V written directly in fragment-linear layout (pack fused into epilogue)
    gemm_qkv<<<dim3(24, 32), 256, 0, stream>>>(Xb, Wqb, Wkb, Wvb, bq, bk, bv, Qb, Kpb, Vpb);

    attn_mfma3<<<dim3(8, BATCH*NHEADS), 512, 0, stream>>>(Qb, Kpb, Vpb, Cb);

    gemm_o<<<dim3(8, 64), 256, 0, stream>>>(Cb, Wob, bo, out);
}